// Round 4
// baseline (2881.398 us; speedup 1.0000x reference)
//
#include <hip/hip_runtime.h>
#include <math.h>

#define N 256
#define Dd 128

__device__ __forceinline__ double inv2s2_of(int s){
    return (s==0)?0.5:(s==1)?5.0e-3:(s==2)?5.0e-5:5.0e-7;
}

// ---------------- gather: z1s = z1[perm1], z2s = z2[perm2] ----------------
__global__ void k_gather(const float* __restrict__ z1, const float* __restrict__ z2,
                         const int* __restrict__ p1, const int* __restrict__ p2,
                         float* __restrict__ z1s, float* __restrict__ z2s){
    int idx = blockIdx.x*256 + threadIdx.x;   // 0 .. 2*N*Dd-1
    int half = N*Dd;
    if (idx < half){
        int i = idx / Dd, t = idx % Dd;
        z1s[idx] = z1[p1[i]*Dd + t];
    } else {
        int j = idx - half;
        int i = j / Dd, t = j % Dd;
        z2s[j] = z2[p2[i]*Dd + t];
    }
}

// ---------------- pairwise squared distances (5 matrices) ----------------
__global__ void k_dist(const float* __restrict__ z1, const float* __restrict__ z2,
                       const float* __restrict__ z1s, const float* __restrict__ z2s,
                       float* __restrict__ Dmat){
    __shared__ float Xs[16][17], Ys[16][17];
    int w = blockIdx.z;
    const float *X1, *Y1, *X2, *Y2; int npair;
    switch(w){
        case 0: X1=z1;  Y1=z1;  X2=z2; Y2=z2;  npair=2; break;
        case 1: X1=z1;  Y1=z1s; X2=z2; Y2=z2s; npair=2; break;
        case 2: X1=z2s; Y1=z2s; X2=0;  Y2=0;   npair=1; break;
        case 3: X1=z2s; Y1=z2;  X2=0;  Y2=0;   npair=1; break;
        default:X1=z1;  Y1=z2;  X2=0;  Y2=0;   npair=1; break;
    }
    int tx = threadIdx.x, ty = threadIdx.y;
    int row = blockIdx.y*16 + ty, col = blockIdx.x*16 + tx;
    double acc = 0.0;
    for (int p = 0; p < npair; p++){
        const float* X = p ? X2 : X1;
        const float* Y = p ? Y2 : Y1;
        for (int c = 0; c < Dd; c += 16){
            __syncthreads();
            Xs[ty][tx] = X[(blockIdx.y*16+ty)*Dd + c + tx];
            Ys[ty][tx] = Y[(blockIdx.x*16+ty)*Dd + c + tx];
            __syncthreads();
            #pragma unroll
            for (int t = 0; t < 16; t++){
                float d = Xs[ty][t] - Ys[tx][t];
                acc += (double)d * (double)d;
            }
        }
    }
    Dmat[w*N*N + row*N + col] = (float)acc;
}

// ---------------- kernel matrices: A (f64, +lam on diag), M/U (f32) ----------------
__global__ void k_kermat(const float* __restrict__ Dmat,
                         double* __restrict__ Aden, double* __restrict__ Anum,
                         float* __restrict__ M4, float* __restrict__ U4){
    int bm = blockIdx.y; int s = bm & 3; int type = bm >> 2;
    int row = blockIdx.x, k = threadIdx.x;
    int dsel = (type==0) ? 2 : (type==1) ? 0 : (type==2) ? 3 : 4;
    double v = exp(-inv2s2_of(s) * (double)Dmat[dsel*N*N + row*N + k]);
    int o = s*N*N + row*N + k;
    if (type == 0){ if (k == row) v += 1.0e-3; Aden[o] = v; }
    else if (type == 1){ if (k == row) v += 1.0e-3; Anum[o] = v; }
    else if (type == 2){ M4[o] = (float)v; }
    else { U4[o] = (float)v; }
}

// ---------------- b_num[s][j] = sum_k exp(-c*Db[j][k]) ----------------
__global__ void k_bnum(const float* __restrict__ Dmat, double* __restrict__ bnum){
    __shared__ double red[256];
    int s = blockIdx.y, j = blockIdx.x, k = threadIdx.x;
    red[k] = exp(-inv2s2_of(s) * (double)Dmat[1*N*N + j*N + k]);
    __syncthreads();
    for (int st = 128; st > 0; st >>= 1){
        if (k < st) red[k] += red[k + st];
        __syncthreads();
    }
    if (k == 0) bnum[s*N + j] = red[0];
}

// ---------------- blocked Gauss-Jordan inversion in f64, G = A^{-1} (f32) --------
// One block (1024 thr) per matrix; matrix lives in GLOBAL f64 scratch S (L2).
// Per block step k (8 steps, BS=32):
//  (a) stage pivot block D into LDS; wave 0 sweeps it elementwise in f64
//      (round-1-verified update formula; wave-lockstep, no block barriers),
//      then negates so P = D^{-1}.
//  (b) C = E * P  (224x32, f64), stored transposed in global scratch.
//  (c) trailing F -= E * C^T (f64, sequential-k accumulation).
//  (d) writeback: col block <- C, row block <- C^T (symmetry), pivot <- -P.
// Final G = -(swept) cast to f32. All arithmetic f64 => blocked cancellation
// errors ~1e-13 (the f32 version of this algebra was catastrophically
// unstable for sigma=1000's near-rank-1 pivot blocks — rounds 2/3 failure).
__launch_bounds__(1024, 1)
__global__ void k_binv(const double* __restrict__ Aden, const double* __restrict__ Anum,
                       double* __restrict__ S8, double* __restrict__ C8,
                       float* __restrict__ Gden, float* __restrict__ Gnum){
    __shared__ double P[32][33];
    int mat = blockIdx.x;
    const double* Asrc = (mat < 4) ? (Aden + (size_t)mat*N*N) : (Anum + (size_t)(mat-4)*N*N);
    double* S = S8 + (size_t)mat*N*N;
    double* C = C8 + (size_t)mat*224*32;   // transposed: C[col*224 + ri]
    float* Gdst = (mat < 4) ? (Gden + (size_t)mat*N*N) : (Gnum + (size_t)(mat-4)*N*N);
    int tid = threadIdx.x;
    int lane = tid & 63;
    int r = lane & 31, cg = lane >> 5;

    // copy A -> S (sweep is destructive; Aden/Anum needed later for IR)
    for (int e = tid; e < N*N; e += 1024) S[e] = Asrc[e];
    __syncthreads();

    for (int k = 0; k < 8; k++){
        int Kb = k*32;
        // ---- (a1) stage pivot block ----
        {
            int i = tid >> 5, j = tid & 31;   // tid covers 32x32 = 1024 exactly
            P[i][j] = S[(size_t)(Kb+i)*N + Kb + j];
        }
        __syncthreads();
        // ---- (a2) wave 0: elementwise f64 sweep of the pivot block ----
        if (tid < 64){
            for (int j = 0; j < 32; j++){
                double d    = P[j][j];
                double invd = 1.0 / d;
                double cr   = P[r][j];
                double s    = cr * invd;
                bool rj = (r == j);
                double nv[16];
                #pragma unroll
                for (int c = 0; c < 16; c++){
                    int col = cg*16 + c;
                    double pj = P[j][col];
                    double v  = P[r][col];
                    nv[c] = rj ? ((col == j) ? -invd : v * invd)
                               : ((col == j) ? s : v - s*pj);
                }
                #pragma unroll
                for (int c = 0; c < 16; c++) P[r][cg*16+c] = nv[c];
            }
            // swept = -D^{-1}; negate so P = D^{-1}
            #pragma unroll
            for (int c = 0; c < 16; c++) P[r][cg*16+c] = -P[r][cg*16+c];
        }
        __syncthreads();
        // ---- (b) C = E * P (rows = 224 non-pivot rows) ----
        for (int e = tid; e < 224*32; e += 1024){
            int ri = e >> 5, col = e & 31;
            int gi = (ri < Kb) ? ri : ri + 32;
            const double* Erow = S + (size_t)gi*N + Kb;
            double acc = 0.0;
            #pragma unroll
            for (int kk = 0; kk < 32; kk++) acc += Erow[kk] * P[kk][col];
            C[col*224 + ri] = acc;
        }
        __syncthreads();
        // ---- (c) trailing: F -= E * C^T ----
        for (int e = tid; e < 224*224; e += 1024){
            int ri = e / 224, rj = e % 224;
            int gi = (ri < Kb) ? ri : ri + 32;
            int gj = (rj < Kb) ? rj : rj + 32;
            const double* Erow = S + (size_t)gi*N + Kb;
            double acc = S[(size_t)gi*N + gj];
            #pragma unroll
            for (int kk = 0; kk < 32; kk++) acc -= Erow[kk] * C[kk*224 + rj];
            S[(size_t)gi*N + gj] = acc;
        }
        __syncthreads();
        // ---- (d) writeback col block, row block (=C^T by symmetry), pivot ----
        for (int e = tid; e < 224*32; e += 1024){
            int ri = e >> 5, c = e & 31;
            int gi = (ri < Kb) ? ri : ri + 32;
            S[(size_t)gi*N + Kb + c] = C[c*224 + ri];
        }
        for (int e = tid; e < 224*32; e += 1024){
            int rj = e % 224, rr = e / 224;   // rr in 0..31
            int gj = (rj < Kb) ? rj : rj + 32;
            S[(size_t)(Kb+rr)*N + gj] = C[rr*224 + rj];
        }
        {
            int i = tid >> 5, j = tid & 31;
            S[(size_t)(Kb+i)*N + Kb + j] = -P[i][j];
        }
        __syncthreads();
    }
    // ---- writeout G = -(swept), cast f32 ----
    for (int e = tid; e < N*N; e += 1024) Gdst[e] = -(float)S[e];
}

// ---------------- B = M * U^T (f32 in, f64 accum/out), batched over sigma --------
__global__ void k_gemm_nt(const float* __restrict__ M4, const float* __restrict__ U4,
                          double* __restrict__ Bmat){
    int s = blockIdx.z;
    const float* Mp = M4 + s*N*N;
    const float* Up = U4 + s*N*N;
    double* Bp = Bmat + s*N*N;
    __shared__ float Ms[32][33], Us[32][33];
    int tx = threadIdx.x, ty = threadIdx.y;
    int tid = ty*16 + tx;
    int bj = blockIdx.y*32, bi = blockIdx.x*32;
    double a00=0, a01=0, a10=0, a11=0;
    for (int kc = 0; kc < N; kc += 32){
        __syncthreads();
        #pragma unroll
        for (int l = 0; l < 4; l++){
            int e = tid + l*256; int r = e >> 5, c = e & 31;
            Ms[r][c] = Mp[(bj+r)*N + kc + c];
            Us[r][c] = Up[(bi+r)*N + kc + c];
        }
        __syncthreads();
        #pragma unroll
        for (int k = 0; k < 32; k++){
            float x0 = Ms[2*ty][k], x1 = Ms[2*ty+1][k];
            float y0 = Us[2*tx][k], y1 = Us[2*tx+1][k];
            a00 += (double)x0*y0; a01 += (double)x0*y1;
            a10 += (double)x1*y0; a11 += (double)x1*y1;
        }
    }
    Bp[(bj+2*ty  )*N + bi+2*tx  ] = a00;
    Bp[(bj+2*ty  )*N + bi+2*tx+1] = a01;
    Bp[(bj+2*ty+1)*N + bi+2*tx  ] = a10;
    Bp[(bj+2*ty+1)*N + bi+2*tx+1] = a11;
}

// ---------------- X0 = G * B  (G f32, B f64 -> X0 f32, f64 accum) ----------------
__global__ void k_gemm_x0(const float* __restrict__ Gden, const double* __restrict__ Bmat,
                          float* __restrict__ X0){
    int s = blockIdx.z;
    const float* Gp = Gden + s*N*N;
    const double* Bp = Bmat + s*N*N;
    float* Xp = X0 + s*N*N;
    __shared__ float Gs[32][33];
    __shared__ double Bs[32][33];
    int tx = threadIdx.x, ty = threadIdx.y;
    int tid = ty*16 + tx;
    int bj = blockIdx.y*32, bi = blockIdx.x*32;
    double a00=0, a01=0, a10=0, a11=0;
    for (int kc = 0; kc < N; kc += 32){
        __syncthreads();
        #pragma unroll
        for (int l = 0; l < 4; l++){
            int e = tid + l*256; int r = e >> 5, c = e & 31;
            Gs[r][c] = Gp[(bj+r)*N + kc + c];
            Bs[r][c] = Bp[(kc+r)*N + bi + c];
        }
        __syncthreads();
        #pragma unroll
        for (int k = 0; k < 32; k++){
            float x0 = Gs[2*ty][k], x1 = Gs[2*ty+1][k];
            double y0 = Bs[k][2*tx], y1 = Bs[k][2*tx+1];
            a00 += (double)x0*y0; a01 += (double)x0*y1;
            a10 += (double)x1*y0; a11 += (double)x1*y1;
        }
    }
    Xp[(bj+2*ty  )*N + bi+2*tx  ] = (float)a00;
    Xp[(bj+2*ty  )*N + bi+2*tx+1] = (float)a01;
    Xp[(bj+2*ty+1)*N + bi+2*tx  ] = (float)a10;
    Xp[(bj+2*ty+1)*N + bi+2*tx+1] = (float)a11;
}

// ---------------- R = B - A * X0  (A f64, X0 f32 -> R f32, f64 accum) ------------
__global__ void k_gemm_r(const double* __restrict__ Aden, const float* __restrict__ X0,
                         const double* __restrict__ Bmat, float* __restrict__ Rm){
    int s = blockIdx.z;
    const double* Ap = Aden + s*N*N;
    const float* Xp = X0 + s*N*N;
    const double* Bp = Bmat + s*N*N;
    float* Rp = Rm + s*N*N;
    __shared__ double As[32][33];
    __shared__ float Xs[32][33];
    int tx = threadIdx.x, ty = threadIdx.y;
    int tid = ty*16 + tx;
    int bj = blockIdx.y*32, bi = blockIdx.x*32;
    double a00=0, a01=0, a10=0, a11=0;
    for (int kc = 0; kc < N; kc += 32){
        __syncthreads();
        #pragma unroll
        for (int l = 0; l < 4; l++){
            int e = tid + l*256; int r = e >> 5, c = e & 31;
            As[r][c] = Ap[(bj+r)*N + kc + c];
            Xs[r][c] = Xp[(kc+r)*N + bi + c];
        }
        __syncthreads();
        #pragma unroll
        for (int k = 0; k < 32; k++){
            double x0 = As[2*ty][k], x1 = As[2*ty+1][k];
            double y0 = (double)Xs[k][2*tx], y1 = (double)Xs[k][2*tx+1];
            a00 += x0*y0; a01 += x0*y1;
            a10 += x1*y0; a11 += x1*y1;
        }
    }
    int r0 = bj+2*ty, c0 = bi+2*tx;
    Rp[(r0  )*N + c0  ] = (float)(Bp[(r0  )*N + c0  ] - a00);
    Rp[(r0  )*N + c0+1] = (float)(Bp[(r0  )*N + c0+1] - a01);
    Rp[(r0+1)*N + c0  ] = (float)(Bp[(r0+1)*N + c0  ] - a10);
    Rp[(r0+1)*N + c0+1] = (float)(Bp[(r0+1)*N + c0+1] - a11);
}

// ---------------- X = X0 + G * R  (all f32, f64 accum) ----------------
__global__ void k_gemm_x(const float* __restrict__ Gden, const float* __restrict__ Rm,
                         const float* __restrict__ X0, float* __restrict__ Xm){
    int s = blockIdx.z;
    const float* Gp = Gden + s*N*N;
    const float* Rp = Rm + s*N*N;
    const float* X0p = X0 + s*N*N;
    float* Xp = Xm + s*N*N;
    __shared__ float Gs[32][33], Rs[32][33];
    int tx = threadIdx.x, ty = threadIdx.y;
    int tid = ty*16 + tx;
    int bj = blockIdx.y*32, bi = blockIdx.x*32;
    double a00=0, a01=0, a10=0, a11=0;
    for (int kc = 0; kc < N; kc += 32){
        __syncthreads();
        #pragma unroll
        for (int l = 0; l < 4; l++){
            int e = tid + l*256; int r = e >> 5, c = e & 31;
            Gs[r][c] = Gp[(bj+r)*N + kc + c];
            Rs[r][c] = Rp[(kc+r)*N + bi + c];
        }
        __syncthreads();
        #pragma unroll
        for (int k = 0; k < 32; k++){
            float x0 = Gs[2*ty][k], x1 = Gs[2*ty+1][k];
            float y0 = Rs[k][2*tx], y1 = Rs[k][2*tx+1];
            a00 += (double)x0*y0; a01 += (double)x0*y1;
            a10 += (double)x1*y0; a11 += (double)x1*y1;
        }
    }
    int r0 = bj+2*ty, c0 = bi+2*tx;
    Xp[(r0  )*N + c0  ] = (float)((double)X0p[(r0  )*N + c0  ] + a00);
    Xp[(r0  )*N + c0+1] = (float)((double)X0p[(r0  )*N + c0+1] + a01);
    Xp[(r0+1)*N + c0  ] = (float)((double)X0p[(r0+1)*N + c0  ] + a10);
    Xp[(r0+1)*N + c0+1] = (float)((double)X0p[(r0+1)*N + c0+1] + a11);
}

// ---------------- numerator solves: y = Gnum*b, + one IR step ----------------
__global__ void k_numsolve(const float* __restrict__ Gnum, const double* __restrict__ Anum,
                           const double* __restrict__ bnum, float* __restrict__ rnum){
    __shared__ double y0[256], rr[256], bsh[256];
    int s = blockIdx.x, j = threadIdx.x;
    const float* Gp = Gnum + s*N*N;
    const double* Ap = Anum + s*N*N;
    const double* bp = bnum + s*N;
    bsh[j] = bp[j];
    __syncthreads();
    double acc = 0;
    for (int k = 0; k < N; k++) acc += (double)Gp[j*N+k] * bsh[k];
    y0[j] = acc;
    __syncthreads();
    acc = 0;
    for (int k = 0; k < N; k++) acc += Ap[j*N+k] * y0[k];
    rr[j] = bsh[j] - acc;
    __syncthreads();
    acc = 0;
    for (int k = 0; k < N; k++) acc += (double)Gp[j*N+k] * rr[k];
    rnum[s*N+j] = (float)(y0[j] + acc);
}

// ---------------- final loss ----------------
__global__ void k_loss(const float* __restrict__ Xm, const float* __restrict__ rnum,
                       float* __restrict__ out){
    __shared__ double red[256];
    int i = threadIdx.x;
    double dsum = 0;
    for (int j = 0; j < N; j++){
        float sx = 0.25f*(Xm[0*N*N + j*N + i] + Xm[1*N*N + j*N + i] +
                          Xm[2*N*N + j*N + i] + Xm[3*N*N + j*N + i]);
        dsum += (double)fmaxf(sx, 0.f);
    }
    double denum = dsum + (double)N * 1.0e-3;
    float ravg = 0.25f*(rnum[0*N+i] + rnum[1*N+i] + rnum[2*N+i] + rnum[3*N+i]);
    double rn = (double)fmaxf(ravg, 0.f) + 1.0e-3;
    red[i] = log(rn) + log(denum);
    __syncthreads();
    for (int st = 128; st > 0; st >>= 1){
        if (i < st) red[i] += red[i + st];
        __syncthreads();
    }
    if (i == 0) out[0] = (float)red[0];
}

extern "C" void kernel_launch(void* const* d_in, const int* in_sizes, int n_in,
                              void* d_out, int out_size, void* d_ws, size_t ws_size,
                              hipStream_t stream) {
    (void)in_sizes; (void)n_in; (void)out_size; (void)ws_size;
    const float* z1 = (const float*)d_in[0];
    const float* z2 = (const float*)d_in[1];
    const int*   p1 = (const int*)d_in[2];
    const int*   p2 = (const int*)d_in[3];
    float* out = (float*)d_out;

    char* w = (char*)d_ws;
    size_t o = 0;
    auto carve = [&](size_t bytes) -> char* {
        char* p = w + o;
        o += (bytes + 255) & ~(size_t)255;
        return p;
    };
    float*  z1s  = (float*) carve(N*Dd*sizeof(float));
    float*  z2s  = (float*) carve(N*Dd*sizeof(float));
    float*  Dmat = (float*) carve((size_t)5*N*N*sizeof(float));
    double* Aden = (double*)carve((size_t)4*N*N*sizeof(double));
    double* Anum = (double*)carve((size_t)4*N*N*sizeof(double));
    float*  M4   = (float*) carve((size_t)4*N*N*sizeof(float));
    float*  U4   = (float*) carve((size_t)4*N*N*sizeof(float));
    double* Bmat = (double*)carve((size_t)4*N*N*sizeof(double));
    float*  Gden = (float*) carve((size_t)4*N*N*sizeof(float));
    float*  Gnum = (float*) carve((size_t)4*N*N*sizeof(float));
    float*  X0   = (float*) carve((size_t)4*N*N*sizeof(float));
    float*  Rm   = (float*) carve((size_t)4*N*N*sizeof(float));
    float*  Xm   = (float*) carve((size_t)4*N*N*sizeof(float));
    double* bnum = (double*)carve((size_t)4*N*sizeof(double));
    float*  rnum = (float*) carve((size_t)4*N*sizeof(float));
    double* Smat = (double*)carve((size_t)8*N*N*sizeof(double));
    double* Cb   = (double*)carve((size_t)8*224*32*sizeof(double));

    k_gather<<<dim3((2*N*Dd)/256), dim3(256), 0, stream>>>(z1, z2, p1, p2, z1s, z2s);
    k_dist<<<dim3(16,16,5), dim3(16,16), 0, stream>>>(z1, z2, z1s, z2s, Dmat);
    k_kermat<<<dim3(N,16), dim3(256), 0, stream>>>(Dmat, Aden, Anum, M4, U4);
    k_bnum<<<dim3(N,4), dim3(256), 0, stream>>>(Dmat, bnum);
    k_binv<<<dim3(8), dim3(1024), 0, stream>>>(Aden, Anum, Smat, Cb, Gden, Gnum);
    k_gemm_nt<<<dim3(8,8,4), dim3(16,16), 0, stream>>>(M4, U4, Bmat);
    k_gemm_x0<<<dim3(8,8,4), dim3(16,16), 0, stream>>>(Gden, Bmat, X0);
    k_gemm_r<<<dim3(8,8,4), dim3(16,16), 0, stream>>>(Aden, X0, Bmat, Rm);
    k_gemm_x<<<dim3(8,8,4), dim3(16,16), 0, stream>>>(Gden, Rm, X0, Xm);
    k_numsolve<<<dim3(4), dim3(256), 0, stream>>>(Gnum, Anum, bnum, rnum);
    k_loss<<<dim3(1), dim3(256), 0, stream>>>(Xm, rnum, out);
}

// Round 5
// 694.038 us; speedup vs baseline: 4.1516x; 4.1516x over previous
//
#include <hip/hip_runtime.h>
#include <math.h>

#define N 256
#define Dd 128

__device__ __forceinline__ double inv2s2_of(int s){
    return (s==0)?0.5:(s==1)?5.0e-3:(s==2)?5.0e-5:5.0e-7;
}

// ---------------- gather: z1s = z1[perm1], z2s = z2[perm2] ----------------
__global__ void k_gather(const float* __restrict__ z1, const float* __restrict__ z2,
                         const int* __restrict__ p1, const int* __restrict__ p2,
                         float* __restrict__ z1s, float* __restrict__ z2s){
    int idx = blockIdx.x*256 + threadIdx.x;   // 0 .. 2*N*Dd-1
    int half = N*Dd;
    if (idx < half){
        int i = idx / Dd, t = idx % Dd;
        z1s[idx] = z1[p1[i]*Dd + t];
    } else {
        int j = idx - half;
        int i = j / Dd, t = j % Dd;
        z2s[j] = z2[p2[i]*Dd + t];
    }
}

// ---------------- pairwise squared distances (5 matrices) ----------------
__global__ void k_dist(const float* __restrict__ z1, const float* __restrict__ z2,
                       const float* __restrict__ z1s, const float* __restrict__ z2s,
                       float* __restrict__ Dmat){
    __shared__ float Xs[16][17], Ys[16][17];
    int w = blockIdx.z;
    const float *X1, *Y1, *X2, *Y2; int npair;
    switch(w){
        case 0: X1=z1;  Y1=z1;  X2=z2; Y2=z2;  npair=2; break;
        case 1: X1=z1;  Y1=z1s; X2=z2; Y2=z2s; npair=2; break;
        case 2: X1=z2s; Y1=z2s; X2=0;  Y2=0;   npair=1; break;
        case 3: X1=z2s; Y1=z2;  X2=0;  Y2=0;   npair=1; break;
        default:X1=z1;  Y1=z2;  X2=0;  Y2=0;   npair=1; break;
    }
    int tx = threadIdx.x, ty = threadIdx.y;
    int row = blockIdx.y*16 + ty, col = blockIdx.x*16 + tx;
    double acc = 0.0;
    for (int p = 0; p < npair; p++){
        const float* X = p ? X2 : X1;
        const float* Y = p ? Y2 : Y1;
        for (int c = 0; c < Dd; c += 16){
            __syncthreads();
            Xs[ty][tx] = X[(blockIdx.y*16+ty)*Dd + c + tx];
            Ys[ty][tx] = Y[(blockIdx.x*16+ty)*Dd + c + tx];
            __syncthreads();
            #pragma unroll
            for (int t = 0; t < 16; t++){
                float d = Xs[ty][t] - Ys[tx][t];
                acc += (double)d * (double)d;
            }
        }
    }
    Dmat[w*N*N + row*N + col] = (float)acc;
}

// ---------------- kernel matrices: A (f64, +lam on diag), M/U (f32) ----------------
__global__ void k_kermat(const float* __restrict__ Dmat,
                         double* __restrict__ Aden, double* __restrict__ Anum,
                         float* __restrict__ M4, float* __restrict__ U4){
    int bm = blockIdx.y; int s = bm & 3; int type = bm >> 2;
    int row = blockIdx.x, k = threadIdx.x;
    int dsel = (type==0) ? 2 : (type==1) ? 0 : (type==2) ? 3 : 4;
    double v = exp(-inv2s2_of(s) * (double)Dmat[dsel*N*N + row*N + k]);
    int o = s*N*N + row*N + k;
    if (type == 0){ if (k == row) v += 1.0e-3; Aden[o] = v; }
    else if (type == 1){ if (k == row) v += 1.0e-3; Anum[o] = v; }
    else if (type == 2){ M4[o] = (float)v; }
    else { U4[o] = (float)v; }
}

// ---------------- b_num[s][j] = sum_k exp(-c*Db[j][k]) ----------------
__global__ void k_bnum(const float* __restrict__ Dmat, double* __restrict__ bnum){
    __shared__ double red[256];
    int s = blockIdx.y, j = blockIdx.x, k = threadIdx.x;
    red[k] = exp(-inv2s2_of(s) * (double)Dmat[1*N*N + j*N + k]);
    __syncthreads();
    for (int st = 128; st > 0; st >>= 1){
        if (k < st) red[k] += red[k + st];
        __syncthreads();
    }
    if (k == 0) bnum[s*N + j] = red[0];
}

// ================= blocked f64 Gauss-Jordan inversion, multi-launch ==========
// Round-4's single-block k_binv was L2-latency-serialized (VALUBusy 0.28%).
// Same (verified) f64 algebra, restructured: per block-step, a panel kernel
// (8 blocks) + a trailing kernel (392 blocks, LDS-staged tiles, 2x2 patches).

// S = A copy (sweep is destructive; Aden/Anum needed for IR later)
__global__ void k_copyS(const double* __restrict__ Aden, const double* __restrict__ Anum,
                        double* __restrict__ S8){
    int idx = blockIdx.x*256 + threadIdx.x;       // 0 .. 8*65536-1
    int mat = idx >> 16, e = idx & 65535;
    S8[idx] = (mat < 4) ? Aden[mat*65536 + e] : Anum[(mat-4)*65536 + e];
}

// panel: stage+sweep pivot (f64, wave 0), save E panel, C = E*P,
// write col/row/pivot blocks of S. Trailing region untouched (k_trail owns it).
__launch_bounds__(1024, 1)
__global__ void k_panel(double* __restrict__ S8, double* __restrict__ Eg,
                        double* __restrict__ Cg, int k){
    __shared__ double P[32][33];
    int mat = blockIdx.x;
    double* S = S8 + (size_t)mat*65536;
    double* E = Eg + (size_t)mat*7168;
    double* C = Cg + (size_t)mat*7168;
    int tid = threadIdx.x;
    int Kb = k*32;
    // stage pivot block (1024 threads cover 32x32 exactly)
    {
        int i = tid >> 5, j = tid & 31;
        P[i][j] = S[(size_t)(Kb+i)*N + Kb + j];
    }
    // save E panel (old col block, compressed rows) to global scratch
    for (int e = tid; e < 7168; e += 1024){
        int ri = e >> 5, kk = e & 31;
        int gi = (ri < Kb) ? ri : ri + 32;
        E[e] = S[(size_t)gi*N + Kb + kk];
    }
    __syncthreads();
    // wave 0: elementwise f64 sweep of pivot block (round-1/4-verified formula)
    if (tid < 64){
        int r = tid & 31, cg = tid >> 5;
        for (int j = 0; j < 32; j++){
            double d    = P[j][j];
            double invd = 1.0 / d;
            double cr   = P[r][j];
            double s    = cr * invd;
            bool rj = (r == j);
            double nv[16];
            #pragma unroll
            for (int c = 0; c < 16; c++){
                int col = cg*16 + c;
                double pj = P[j][col];
                double v  = P[r][col];
                nv[c] = rj ? ((col == j) ? -invd : v * invd)
                           : ((col == j) ? s : v - s*pj);
            }
            #pragma unroll
            for (int c = 0; c < 16; c++) P[r][cg*16+c] = nv[c];
        }
        // swept = -D^{-1}; negate so P = D^{-1}
        #pragma unroll
        for (int c = 0; c < 16; c++) P[r][cg*16+c] = -P[r][cg*16+c];
    }
    __syncthreads();
    // C = E * P; write C (row-major [ri][col]) and the new col block of S
    for (int e = tid; e < 7168; e += 1024){
        int ri = e >> 5, col = e & 31;
        const double* Erow = E + ri*32;
        double acc = 0.0;
        #pragma unroll
        for (int kk = 0; kk < 32; kk++) acc += Erow[kk] * P[kk][col];
        C[e] = acc;
        int gi = (ri < Kb) ? ri : ri + 32;
        S[(size_t)gi*N + Kb + col] = acc;
    }
    __syncthreads();
    // row block <- C^T (symmetry), pivot <- -P
    for (int e = tid; e < 7168; e += 1024){
        int rr = e / 224, rj = e % 224;
        int gj = (rj < Kb) ? rj : rj + 32;
        S[(size_t)(Kb+rr)*N + gj] = C[rj*32 + rr];
    }
    {
        int i = tid >> 5, j = tid & 31;
        S[(size_t)(Kb+i)*N + Kb + j] = -P[i][j];
    }
}

// trailing: F -= E * C^T, one 32x32 tile per block (49 tiles x 8 matrices),
// E/C tiles staged in LDS, 2x2 register patches, direct RMW of S.
__global__ void k_trail(double* __restrict__ S8, const double* __restrict__ Eg,
                        const double* __restrict__ Cg, int k){
    __shared__ double El[32][33], Cl[32][33];
    int t = blockIdx.x;
    int I = t / 7, J = t % 7;
    int mat = blockIdx.y;
    double* S = S8 + (size_t)mat*65536;
    const double* E = Eg + (size_t)mat*7168;
    const double* C = Cg + (size_t)mat*7168;
    int tid = threadIdx.x;
    int Kb = k*32;
    #pragma unroll
    for (int l = 0; l < 4; l++){
        int e = tid + l*256; int r = e >> 5, kk = e & 31;
        El[r][kk] = E[(I*32 + r)*32 + kk];
        Cl[r][kk] = C[(J*32 + r)*32 + kk];
    }
    __syncthreads();
    int pr = tid >> 4, pc = tid & 15;
    int r0 = 2*pr, c0 = 2*pc;
    double a00=0, a01=0, a10=0, a11=0;
    #pragma unroll
    for (int kk = 0; kk < 32; kk++){
        double e0 = El[r0][kk],   e1 = El[r0+1][kk];
        double b0 = Cl[c0][kk],   b1 = Cl[c0+1][kk];
        a00 += e0*b0; a01 += e0*b1;
        a10 += e1*b0; a11 += e1*b1;
    }
    int ci0 = I*32 + r0, cj0 = J*32 + c0;
    int gi0 = (ci0   < Kb) ? ci0   : ci0+32;
    int gi1 = (ci0+1 < Kb) ? ci0+1 : ci0+33;
    int gj0 = (cj0   < Kb) ? cj0   : cj0+32;
    int gj1 = (cj0+1 < Kb) ? cj0+1 : cj0+33;
    S[(size_t)gi0*N + gj0] -= a00;
    S[(size_t)gi0*N + gj1] -= a01;
    S[(size_t)gi1*N + gj0] -= a10;
    S[(size_t)gi1*N + gj1] -= a11;
}

// writeout: G = -(swept), cast f32
__global__ void k_gout(const double* __restrict__ S8,
                       float* __restrict__ Gden, float* __restrict__ Gnum){
    int idx = blockIdx.x*256 + threadIdx.x;
    int mat = idx >> 16, e = idx & 65535;
    float g = -(float)S8[idx];
    if (mat < 4) Gden[mat*65536 + e] = g;
    else         Gnum[(mat-4)*65536 + e] = g;
}

// ---------------- B = M * U^T (f32 in, f64 accum/out), batched over sigma --------
__global__ void k_gemm_nt(const float* __restrict__ M4, const float* __restrict__ U4,
                          double* __restrict__ Bmat){
    int s = blockIdx.z;
    const float* Mp = M4 + s*N*N;
    const float* Up = U4 + s*N*N;
    double* Bp = Bmat + s*N*N;
    __shared__ float Ms[32][33], Us[32][33];
    int tx = threadIdx.x, ty = threadIdx.y;
    int tid = ty*16 + tx;
    int bj = blockIdx.y*32, bi = blockIdx.x*32;
    double a00=0, a01=0, a10=0, a11=0;
    for (int kc = 0; kc < N; kc += 32){
        __syncthreads();
        #pragma unroll
        for (int l = 0; l < 4; l++){
            int e = tid + l*256; int r = e >> 5, c = e & 31;
            Ms[r][c] = Mp[(bj+r)*N + kc + c];
            Us[r][c] = Up[(bi+r)*N + kc + c];
        }
        __syncthreads();
        #pragma unroll
        for (int k = 0; k < 32; k++){
            float x0 = Ms[2*ty][k], x1 = Ms[2*ty+1][k];
            float y0 = Us[2*tx][k], y1 = Us[2*tx+1][k];
            a00 += (double)x0*y0; a01 += (double)x0*y1;
            a10 += (double)x1*y0; a11 += (double)x1*y1;
        }
    }
    Bp[(bj+2*ty  )*N + bi+2*tx  ] = a00;
    Bp[(bj+2*ty  )*N + bi+2*tx+1] = a01;
    Bp[(bj+2*ty+1)*N + bi+2*tx  ] = a10;
    Bp[(bj+2*ty+1)*N + bi+2*tx+1] = a11;
}

// ---------------- X0 = G * B  (G f32, B f64 -> X0 f32, f64 accum) ----------------
__global__ void k_gemm_x0(const float* __restrict__ Gden, const double* __restrict__ Bmat,
                          float* __restrict__ X0){
    int s = blockIdx.z;
    const float* Gp = Gden + s*N*N;
    const double* Bp = Bmat + s*N*N;
    float* Xp = X0 + s*N*N;
    __shared__ float Gs[32][33];
    __shared__ double Bs[32][33];
    int tx = threadIdx.x, ty = threadIdx.y;
    int tid = ty*16 + tx;
    int bj = blockIdx.y*32, bi = blockIdx.x*32;
    double a00=0, a01=0, a10=0, a11=0;
    for (int kc = 0; kc < N; kc += 32){
        __syncthreads();
        #pragma unroll
        for (int l = 0; l < 4; l++){
            int e = tid + l*256; int r = e >> 5, c = e & 31;
            Gs[r][c] = Gp[(bj+r)*N + kc + c];
            Bs[r][c] = Bp[(kc+r)*N + bi + c];
        }
        __syncthreads();
        #pragma unroll
        for (int k = 0; k < 32; k++){
            float x0 = Gs[2*ty][k], x1 = Gs[2*ty+1][k];
            double y0 = Bs[k][2*tx], y1 = Bs[k][2*tx+1];
            a00 += (double)x0*y0; a01 += (double)x0*y1;
            a10 += (double)x1*y0; a11 += (double)x1*y1;
        }
    }
    Xp[(bj+2*ty  )*N + bi+2*tx  ] = (float)a00;
    Xp[(bj+2*ty  )*N + bi+2*tx+1] = (float)a01;
    Xp[(bj+2*ty+1)*N + bi+2*tx  ] = (float)a10;
    Xp[(bj+2*ty+1)*N + bi+2*tx+1] = (float)a11;
}

// ---------------- R = B - A * X0  (A f64, X0 f32 -> R f32, f64 accum) ------------
__global__ void k_gemm_r(const double* __restrict__ Aden, const float* __restrict__ X0,
                         const double* __restrict__ Bmat, float* __restrict__ Rm){
    int s = blockIdx.z;
    const double* Ap = Aden + s*N*N;
    const float* Xp = X0 + s*N*N;
    const double* Bp = Bmat + s*N*N;
    float* Rp = Rm + s*N*N;
    __shared__ double As[32][33];
    __shared__ float Xs[32][33];
    int tx = threadIdx.x, ty = threadIdx.y;
    int tid = ty*16 + tx;
    int bj = blockIdx.y*32, bi = blockIdx.x*32;
    double a00=0, a01=0, a10=0, a11=0;
    for (int kc = 0; kc < N; kc += 32){
        __syncthreads();
        #pragma unroll
        for (int l = 0; l < 4; l++){
            int e = tid + l*256; int r = e >> 5, c = e & 31;
            As[r][c] = Ap[(bj+r)*N + kc + c];
            Xs[r][c] = Xp[(kc+r)*N + bi + c];
        }
        __syncthreads();
        #pragma unroll
        for (int k = 0; k < 32; k++){
            double x0 = As[2*ty][k], x1 = As[2*ty+1][k];
            double y0 = (double)Xs[k][2*tx], y1 = (double)Xs[k][2*tx+1];
            a00 += x0*y0; a01 += x0*y1;
            a10 += x1*y0; a11 += x1*y1;
        }
    }
    int r0 = bj+2*ty, c0 = bi+2*tx;
    Rp[(r0  )*N + c0  ] = (float)(Bp[(r0  )*N + c0  ] - a00);
    Rp[(r0  )*N + c0+1] = (float)(Bp[(r0  )*N + c0+1] - a01);
    Rp[(r0+1)*N + c0  ] = (float)(Bp[(r0+1)*N + c0  ] - a10);
    Rp[(r0+1)*N + c0+1] = (float)(Bp[(r0+1)*N + c0+1] - a11);
}

// ---------------- X = X0 + G * R  (all f32, f64 accum) ----------------
__global__ void k_gemm_x(const float* __restrict__ Gden, const float* __restrict__ Rm,
                         const float* __restrict__ X0, float* __restrict__ Xm){
    int s = blockIdx.z;
    const float* Gp = Gden + s*N*N;
    const float* Rp = Rm + s*N*N;
    const float* X0p = X0 + s*N*N;
    float* Xp = Xm + s*N*N;
    __shared__ float Gs[32][33], Rs[32][33];
    int tx = threadIdx.x, ty = threadIdx.y;
    int tid = ty*16 + tx;
    int bj = blockIdx.y*32, bi = blockIdx.x*32;
    double a00=0, a01=0, a10=0, a11=0;
    for (int kc = 0; kc < N; kc += 32){
        __syncthreads();
        #pragma unroll
        for (int l = 0; l < 4; l++){
            int e = tid + l*256; int r = e >> 5, c = e & 31;
            Gs[r][c] = Gp[(bj+r)*N + kc + c];
            Rs[r][c] = Rp[(kc+r)*N + bi + c];
        }
        __syncthreads();
        #pragma unroll
        for (int k = 0; k < 32; k++){
            float x0 = Gs[2*ty][k], x1 = Gs[2*ty+1][k];
            float y0 = Rs[k][2*tx], y1 = Rs[k][2*tx+1];
            a00 += (double)x0*y0; a01 += (double)x0*y1;
            a10 += (double)x1*y0; a11 += (double)x1*y1;
        }
    }
    int r0 = bj+2*ty, c0 = bi+2*tx;
    Xp[(r0  )*N + c0  ] = (float)((double)X0p[(r0  )*N + c0  ] + a00);
    Xp[(r0  )*N + c0+1] = (float)((double)X0p[(r0  )*N + c0+1] + a01);
    Xp[(r0+1)*N + c0  ] = (float)((double)X0p[(r0+1)*N + c0  ] + a10);
    Xp[(r0+1)*N + c0+1] = (float)((double)X0p[(r0+1)*N + c0+1] + a11);
}

// ---------------- numerator solves: y = Gnum*b, + one IR step ----------------
__global__ void k_numsolve(const float* __restrict__ Gnum, const double* __restrict__ Anum,
                           const double* __restrict__ bnum, float* __restrict__ rnum){
    __shared__ double y0[256], rr[256], bsh[256];
    int s = blockIdx.x, j = threadIdx.x;
    const float* Gp = Gnum + s*N*N;
    const double* Ap = Anum + s*N*N;
    const double* bp = bnum + s*N;
    bsh[j] = bp[j];
    __syncthreads();
    double acc = 0;
    for (int k = 0; k < N; k++) acc += (double)Gp[j*N+k] * bsh[k];
    y0[j] = acc;
    __syncthreads();
    acc = 0;
    for (int k = 0; k < N; k++) acc += Ap[j*N+k] * y0[k];
    rr[j] = bsh[j] - acc;
    __syncthreads();
    acc = 0;
    for (int k = 0; k < N; k++) acc += (double)Gp[j*N+k] * rr[k];
    rnum[s*N+j] = (float)(y0[j] + acc);
}

// ---------------- final loss ----------------
__global__ void k_loss(const float* __restrict__ Xm, const float* __restrict__ rnum,
                       float* __restrict__ out){
    __shared__ double red[256];
    int i = threadIdx.x;
    double dsum = 0;
    for (int j = 0; j < N; j++){
        float sx = 0.25f*(Xm[0*N*N + j*N + i] + Xm[1*N*N + j*N + i] +
                          Xm[2*N*N + j*N + i] + Xm[3*N*N + j*N + i]);
        dsum += (double)fmaxf(sx, 0.f);
    }
    double denum = dsum + (double)N * 1.0e-3;
    float ravg = 0.25f*(rnum[0*N+i] + rnum[1*N+i] + rnum[2*N+i] + rnum[3*N+i]);
    double rn = (double)fmaxf(ravg, 0.f) + 1.0e-3;
    red[i] = log(rn) + log(denum);
    __syncthreads();
    for (int st = 128; st > 0; st >>= 1){
        if (i < st) red[i] += red[i + st];
        __syncthreads();
    }
    if (i == 0) out[0] = (float)red[0];
}

extern "C" void kernel_launch(void* const* d_in, const int* in_sizes, int n_in,
                              void* d_out, int out_size, void* d_ws, size_t ws_size,
                              hipStream_t stream) {
    (void)in_sizes; (void)n_in; (void)out_size; (void)ws_size;
    const float* z1 = (const float*)d_in[0];
    const float* z2 = (const float*)d_in[1];
    const int*   p1 = (const int*)d_in[2];
    const int*   p2 = (const int*)d_in[3];
    float* out = (float*)d_out;

    char* w = (char*)d_ws;
    size_t o = 0;
    auto carve = [&](size_t bytes) -> char* {
        char* p = w + o;
        o += (bytes + 255) & ~(size_t)255;
        return p;
    };
    float*  z1s  = (float*) carve(N*Dd*sizeof(float));
    float*  z2s  = (float*) carve(N*Dd*sizeof(float));
    float*  Dmat = (float*) carve((size_t)5*N*N*sizeof(float));
    double* Aden = (double*)carve((size_t)4*N*N*sizeof(double));
    double* Anum = (double*)carve((size_t)4*N*N*sizeof(double));
    float*  M4   = (float*) carve((size_t)4*N*N*sizeof(float));
    float*  U4   = (float*) carve((size_t)4*N*N*sizeof(float));
    double* Bmat = (double*)carve((size_t)4*N*N*sizeof(double));
    float*  Gden = (float*) carve((size_t)4*N*N*sizeof(float));
    float*  Gnum = (float*) carve((size_t)4*N*N*sizeof(float));
    float*  X0   = (float*) carve((size_t)4*N*N*sizeof(float));
    float*  Rm   = (float*) carve((size_t)4*N*N*sizeof(float));
    float*  Xm   = (float*) carve((size_t)4*N*N*sizeof(float));
    double* bnum = (double*)carve((size_t)4*N*sizeof(double));
    float*  rnum = (float*) carve((size_t)4*N*sizeof(float));
    double* Smat = (double*)carve((size_t)8*N*N*sizeof(double));
    double* Eg   = (double*)carve((size_t)8*224*32*sizeof(double));
    double* Cg   = (double*)carve((size_t)8*224*32*sizeof(double));

    k_gather<<<dim3((2*N*Dd)/256), dim3(256), 0, stream>>>(z1, z2, p1, p2, z1s, z2s);
    k_dist<<<dim3(16,16,5), dim3(16,16), 0, stream>>>(z1, z2, z1s, z2s, Dmat);
    k_kermat<<<dim3(N,16), dim3(256), 0, stream>>>(Dmat, Aden, Anum, M4, U4);
    k_bnum<<<dim3(N,4), dim3(256), 0, stream>>>(Dmat, bnum);

    k_copyS<<<dim3(2048), dim3(256), 0, stream>>>(Aden, Anum, Smat);
    for (int k = 0; k < 8; k++){
        k_panel<<<dim3(8), dim3(1024), 0, stream>>>(Smat, Eg, Cg, k);
        k_trail<<<dim3(49,8), dim3(256), 0, stream>>>(Smat, Eg, Cg, k);
    }
    k_gout<<<dim3(2048), dim3(256), 0, stream>>>(Smat, Gden, Gnum);

    k_gemm_nt<<<dim3(8,8,4), dim3(16,16), 0, stream>>>(M4, U4, Bmat);
    k_gemm_x0<<<dim3(8,8,4), dim3(16,16), 0, stream>>>(Gden, Bmat, X0);
    k_gemm_r<<<dim3(8,8,4), dim3(16,16), 0, stream>>>(Aden, X0, Bmat, Rm);
    k_gemm_x<<<dim3(8,8,4), dim3(16,16), 0, stream>>>(Gden, Rm, X0, Xm);
    k_numsolve<<<dim3(4), dim3(256), 0, stream>>>(Gnum, Anum, bnum, rnum);
    k_loss<<<dim3(1), dim3(256), 0, stream>>>(Xm, rnum, out);
}

// Round 6
// 559.007 us; speedup vs baseline: 5.1545x; 1.2416x over previous
//
#include <hip/hip_runtime.h>
#include <math.h>

#define N 256
#define Dd 128

__device__ __forceinline__ double inv2s2_of(int s){
    return (s==0)?0.5:(s==1)?5.0e-3:(s==2)?5.0e-5:5.0e-7;
}

// ---------------- gather: z1s = z1[perm1], z2s = z2[perm2] ----------------
__global__ void k_gather(const float* __restrict__ z1, const float* __restrict__ z2,
                         const int* __restrict__ p1, const int* __restrict__ p2,
                         float* __restrict__ z1s, float* __restrict__ z2s){
    int idx = blockIdx.x*256 + threadIdx.x;   // 0 .. 2*N*Dd-1
    int half = N*Dd;
    if (idx < half){
        int i = idx / Dd, t = idx % Dd;
        z1s[idx] = z1[p1[i]*Dd + t];
    } else {
        int j = idx - half;
        int i = j / Dd, t = j % Dd;
        z2s[j] = z2[p2[i]*Dd + t];
    }
}

// ---------------- pairwise squared distances (5 matrices) ----------------
__global__ void k_dist(const float* __restrict__ z1, const float* __restrict__ z2,
                       const float* __restrict__ z1s, const float* __restrict__ z2s,
                       float* __restrict__ Dmat){
    __shared__ float Xs[16][17], Ys[16][17];
    int w = blockIdx.z;
    const float *X1, *Y1, *X2, *Y2; int npair;
    switch(w){
        case 0: X1=z1;  Y1=z1;  X2=z2; Y2=z2;  npair=2; break;
        case 1: X1=z1;  Y1=z1s; X2=z2; Y2=z2s; npair=2; break;
        case 2: X1=z2s; Y1=z2s; X2=0;  Y2=0;   npair=1; break;
        case 3: X1=z2s; Y1=z2;  X2=0;  Y2=0;   npair=1; break;
        default:X1=z1;  Y1=z2;  X2=0;  Y2=0;   npair=1; break;
    }
    int tx = threadIdx.x, ty = threadIdx.y;
    int row = blockIdx.y*16 + ty, col = blockIdx.x*16 + tx;
    double acc = 0.0;
    for (int p = 0; p < npair; p++){
        const float* X = p ? X2 : X1;
        const float* Y = p ? Y2 : Y1;
        for (int c = 0; c < Dd; c += 16){
            __syncthreads();
            Xs[ty][tx] = X[(blockIdx.y*16+ty)*Dd + c + tx];
            Ys[ty][tx] = Y[(blockIdx.x*16+ty)*Dd + c + tx];
            __syncthreads();
            #pragma unroll
            for (int t = 0; t < 16; t++){
                float d = Xs[ty][t] - Ys[tx][t];
                acc += (double)d * (double)d;
            }
        }
    }
    Dmat[w*N*N + row*N + col] = (float)acc;
}

// ------- kernel matrices: A (f64, +lam diag), M/U (f32); also seeds S=A -------
__global__ void k_kermat(const float* __restrict__ Dmat,
                         double* __restrict__ Aden, double* __restrict__ Anum,
                         float* __restrict__ M4, float* __restrict__ U4,
                         double* __restrict__ S8){
    int bm = blockIdx.y; int s = bm & 3; int type = bm >> 2;
    int row = blockIdx.x, kcol = threadIdx.x;
    int dsel = (type==0) ? 2 : (type==1) ? 0 : (type==2) ? 3 : 4;
    double v = exp(-inv2s2_of(s) * (double)Dmat[dsel*N*N + row*N + kcol]);
    int o = s*N*N + row*N + kcol;
    if (type == 0){ if (kcol == row) v += 1.0e-3; Aden[o] = v; S8[o] = v; }
    else if (type == 1){ if (kcol == row) v += 1.0e-3; Anum[o] = v; S8[4*N*N + o] = v; }
    else if (type == 2){ M4[o] = (float)v; }
    else { U4[o] = (float)v; }
}

// ---------------- b_num[s][j] = sum_k exp(-c*Db[j][k]) ----------------
__global__ void k_bnum(const float* __restrict__ Dmat, double* __restrict__ bnum){
    __shared__ double red[256];
    int s = blockIdx.y, j = blockIdx.x, k = threadIdx.x;
    red[k] = exp(-inv2s2_of(s) * (double)Dmat[1*N*N + j*N + k]);
    __syncthreads();
    for (int st = 128; st > 0; st >>= 1){
        if (k < st) red[k] += red[k + st];
        __syncthreads();
    }
    if (k == 0) bnum[s*N + j] = red[0];
}

// ================= blocked f64 Gauss-Jordan inversion, multi-launch ==========
// Round-5's k_panel computed C=E*P with E read from GLOBAL in the inner loop
// (8 blocks, latency-serialized, 58us each). Fix: k_pivot only stages E and
// sweeps the pivot; the C computation moves into k_step, which stages ALL
// operands in LDS and runs 448 blocks chip-wide (each trailing block
// recomputes its C_J tile in-LDS: 32K f64 FMA, cheaper than a global trip).

// pivot: stage E panel -> Eg, stage+sweep pivot in LDS (wave 0, f64,
// round-1/4-verified formula), P -> Pg, -P -> S pivot block.
__launch_bounds__(1024, 1)
__global__ void k_pivot(double* __restrict__ S8, double* __restrict__ Eg,
                        double* __restrict__ Pg, int k){
    __shared__ double P[32][33];
    int mat = blockIdx.x;
    double* S = S8 + (size_t)mat*65536;
    double* E = Eg + (size_t)mat*7168;
    double* Pp = Pg + (size_t)mat*1024;
    int tid = threadIdx.x;
    int Kb = k*32;
    // stage pivot block (1024 threads cover 32x32 exactly)
    {
        int i = tid >> 5, j = tid & 31;
        P[i][j] = S[(size_t)(Kb+i)*N + Kb + j];
    }
    // stage E panel (old col block, compressed rows) -> Eg
    for (int e = tid; e < 7168; e += 1024){
        int ri = e >> 5, kk = e & 31;
        int gi = (ri < Kb) ? ri : ri + 32;
        E[e] = S[(size_t)gi*N + Kb + kk];
    }
    __syncthreads();
    // wave 0: elementwise f64 sweep of pivot block
    if (tid < 64){
        int r = tid & 31, cg = tid >> 5;
        for (int j = 0; j < 32; j++){
            double d    = P[j][j];
            double invd = 1.0 / d;
            double cr   = P[r][j];
            double s    = cr * invd;
            bool rj = (r == j);
            double nv[16];
            #pragma unroll
            for (int c = 0; c < 16; c++){
                int col = cg*16 + c;
                double pj = P[j][col];
                double v  = P[r][col];
                nv[c] = rj ? ((col == j) ? -invd : v * invd)
                           : ((col == j) ? s : v - s*pj);
            }
            #pragma unroll
            for (int c = 0; c < 16; c++) P[r][cg*16+c] = nv[c];
        }
        // swept = -D^{-1}; negate so P = D^{-1}
        #pragma unroll
        for (int c = 0; c < 16; c++) P[r][cg*16+c] = -P[r][cg*16+c];
    }
    __syncthreads();
    // P -> Pg ; -P -> S pivot block
    {
        int i = tid >> 5, j = tid & 31;
        Pp[tid] = P[i][j];
        S[(size_t)(Kb+i)*N + Kb + j] = -P[i][j];
    }
}

// step: blocks 0..48 trailing (I,J): C_J = E_J*P in LDS, F_IJ -= E_I * C_J^T.
//       blocks 49..55 colrow T: C_T = E_T*P, write col tile + row tile (C^T).
__launch_bounds__(256, 4)
__global__ void k_step(double* __restrict__ S8, const double* __restrict__ Eg,
                       const double* __restrict__ Pg, int k){
    __shared__ double Pl[32][33], EJ[32][33], Cl[32][33], El[32][33];
    int bx = blockIdx.x, mat = blockIdx.y;
    double* S = S8 + (size_t)mat*65536;
    const double* E = Eg + (size_t)mat*7168;
    const double* Pp = Pg + (size_t)mat*1024;
    int tid = threadIdx.x;
    int Kb = k*32;
    // load P
    #pragma unroll
    for (int l = 0; l < 4; l++){
        int e = tid + l*256; int i = e >> 5, j = e & 31;
        Pl[i][j] = Pp[e];
    }
    if (bx < 49){
        int I = bx / 7, J = bx % 7;
        #pragma unroll
        for (int l = 0; l < 4; l++){
            int e = tid + l*256; int r = e >> 5, kk = e & 31;
            El[r][kk] = E[(I*32 + r)*32 + kk];
            EJ[r][kk] = E[(J*32 + r)*32 + kk];
        }
        __syncthreads();
        // C_J = E_J * P
        #pragma unroll
        for (int l = 0; l < 4; l++){
            int e = tid + l*256; int r = e >> 5, c = e & 31;
            double acc = 0.0;
            #pragma unroll
            for (int kk = 0; kk < 32; kk++) acc += EJ[r][kk] * Pl[kk][c];
            Cl[r][c] = acc;
        }
        __syncthreads();
        // trailing: F_IJ -= E_I * C_J^T   (2x2 register patches)
        int pr = tid >> 4, pc = tid & 15;
        int r0 = 2*pr, c0 = 2*pc;
        double a00=0, a01=0, a10=0, a11=0;
        #pragma unroll
        for (int kk = 0; kk < 32; kk++){
            double e0 = El[r0][kk],   e1 = El[r0+1][kk];
            double b0 = Cl[c0][kk],   b1 = Cl[c0+1][kk];
            a00 += e0*b0; a01 += e0*b1;
            a10 += e1*b0; a11 += e1*b1;
        }
        int gI = (I*32 < Kb) ? I*32 : I*32 + 32;
        int gJ = (J*32 < Kb) ? J*32 : J*32 + 32;
        double* Sp = S + (size_t)(gI + r0)*N + gJ + c0;
        Sp[0]   -= a00; Sp[1]   -= a01;
        Sp[N]   -= a10; Sp[N+1] -= a11;
    } else {
        int T = bx - 49;
        #pragma unroll
        for (int l = 0; l < 4; l++){
            int e = tid + l*256; int r = e >> 5, kk = e & 31;
            El[r][kk] = E[(T*32 + r)*32 + kk];
        }
        __syncthreads();
        // C_T = E_T * P -> LDS
        #pragma unroll
        for (int l = 0; l < 4; l++){
            int e = tid + l*256; int r = e >> 5, c = e & 31;
            double acc = 0.0;
            #pragma unroll
            for (int kk = 0; kk < 32; kk++) acc += El[r][kk] * Pl[kk][c];
            Cl[r][c] = acc;
        }
        __syncthreads();
        int gT = (T*32 < Kb) ? T*32 : T*32 + 32;
        // col block tile: S[gT+r][Kb+c] = C[r][c]  (coalesced)
        #pragma unroll
        for (int l = 0; l < 4; l++){
            int e = tid + l*256; int r = e >> 5, c = e & 31;
            S[(size_t)(gT + r)*N + Kb + c] = Cl[r][c];
        }
        // row block tile: S[Kb+c][gT+r] = C[r][c]  (coalesced via transpose read)
        #pragma unroll
        for (int l = 0; l < 4; l++){
            int e = tid + l*256; int cc = e >> 5, rr = e & 31;
            S[(size_t)(Kb + cc)*N + gT + rr] = Cl[rr][cc];
        }
    }
}

// writeout: G = -(swept), cast f32
__global__ void k_gout(const double* __restrict__ S8,
                       float* __restrict__ Gden, float* __restrict__ Gnum){
    int idx = blockIdx.x*256 + threadIdx.x;
    int mat = idx >> 16, e = idx & 65535;
    float g = -(float)S8[idx];
    if (mat < 4) Gden[mat*65536 + e] = g;
    else         Gnum[(mat-4)*65536 + e] = g;
}

// ---------------- B = M * U^T (f32 in, f64 accum/out), batched over sigma --------
__global__ void k_gemm_nt(const float* __restrict__ M4, const float* __restrict__ U4,
                          double* __restrict__ Bmat){
    int s = blockIdx.z;
    const float* Mp = M4 + s*N*N;
    const float* Up = U4 + s*N*N;
    double* Bp = Bmat + s*N*N;
    __shared__ float Ms[32][33], Us[32][33];
    int tx = threadIdx.x, ty = threadIdx.y;
    int tid = ty*16 + tx;
    int bj = blockIdx.y*32, bi = blockIdx.x*32;
    double a00=0, a01=0, a10=0, a11=0;
    for (int kc = 0; kc < N; kc += 32){
        __syncthreads();
        #pragma unroll
        for (int l = 0; l < 4; l++){
            int e = tid + l*256; int r = e >> 5, c = e & 31;
            Ms[r][c] = Mp[(bj+r)*N + kc + c];
            Us[r][c] = Up[(bi+r)*N + kc + c];
        }
        __syncthreads();
        #pragma unroll
        for (int k = 0; k < 32; k++){
            float x0 = Ms[2*ty][k], x1 = Ms[2*ty+1][k];
            float y0 = Us[2*tx][k], y1 = Us[2*tx+1][k];
            a00 += (double)x0*y0; a01 += (double)x0*y1;
            a10 += (double)x1*y0; a11 += (double)x1*y1;
        }
    }
    Bp[(bj+2*ty  )*N + bi+2*tx  ] = a00;
    Bp[(bj+2*ty  )*N + bi+2*tx+1] = a01;
    Bp[(bj+2*ty+1)*N + bi+2*tx  ] = a10;
    Bp[(bj+2*ty+1)*N + bi+2*tx+1] = a11;
}

// ---------------- X0 = G * B  (G f32, B f64 -> X0 f32, f64 accum) ----------------
__global__ void k_gemm_x0(const float* __restrict__ Gden, const double* __restrict__ Bmat,
                          float* __restrict__ X0){
    int s = blockIdx.z;
    const float* Gp = Gden + s*N*N;
    const double* Bp = Bmat + s*N*N;
    float* Xp = X0 + s*N*N;
    __shared__ float Gs[32][33];
    __shared__ double Bs[32][33];
    int tx = threadIdx.x, ty = threadIdx.y;
    int tid = ty*16 + tx;
    int bj = blockIdx.y*32, bi = blockIdx.x*32;
    double a00=0, a01=0, a10=0, a11=0;
    for (int kc = 0; kc < N; kc += 32){
        __syncthreads();
        #pragma unroll
        for (int l = 0; l < 4; l++){
            int e = tid + l*256; int r = e >> 5, c = e & 31;
            Gs[r][c] = Gp[(bj+r)*N + kc + c];
            Bs[r][c] = Bp[(kc+r)*N + bi + c];
        }
        __syncthreads();
        #pragma unroll
        for (int k = 0; k < 32; k++){
            float x0 = Gs[2*ty][k], x1 = Gs[2*ty+1][k];
            double y0 = Bs[k][2*tx], y1 = Bs[k][2*tx+1];
            a00 += (double)x0*y0; a01 += (double)x0*y1;
            a10 += (double)x1*y0; a11 += (double)x1*y1;
        }
    }
    Xp[(bj+2*ty  )*N + bi+2*tx  ] = (float)a00;
    Xp[(bj+2*ty  )*N + bi+2*tx+1] = (float)a01;
    Xp[(bj+2*ty+1)*N + bi+2*tx  ] = (float)a10;
    Xp[(bj+2*ty+1)*N + bi+2*tx+1] = (float)a11;
}

// ---------------- R = B - A * X0  (A f64, X0 f32 -> R f32, f64 accum) ------------
__global__ void k_gemm_r(const double* __restrict__ Aden, const float* __restrict__ X0,
                         const double* __restrict__ Bmat, float* __restrict__ Rm){
    int s = blockIdx.z;
    const double* Ap = Aden + s*N*N;
    const float* Xp = X0 + s*N*N;
    const double* Bp = Bmat + s*N*N;
    float* Rp = Rm + s*N*N;
    __shared__ double As[32][33];
    __shared__ float Xs[32][33];
    int tx = threadIdx.x, ty = threadIdx.y;
    int tid = ty*16 + tx;
    int bj = blockIdx.y*32, bi = blockIdx.x*32;
    double a00=0, a01=0, a10=0, a11=0;
    for (int kc = 0; kc < N; kc += 32){
        __syncthreads();
        #pragma unroll
        for (int l = 0; l < 4; l++){
            int e = tid + l*256; int r = e >> 5, c = e & 31;
            As[r][c] = Ap[(bj+r)*N + kc + c];
            Xs[r][c] = Xp[(kc+r)*N + bi + c];
        }
        __syncthreads();
        #pragma unroll
        for (int k = 0; k < 32; k++){
            double x0 = As[2*ty][k], x1 = As[2*ty+1][k];
            double y0 = (double)Xs[k][2*tx], y1 = (double)Xs[k][2*tx+1];
            a00 += x0*y0; a01 += x0*y1;
            a10 += x1*y0; a11 += x1*y1;
        }
    }
    int r0 = bj+2*ty, c0 = bi+2*tx;
    Rp[(r0  )*N + c0  ] = (float)(Bp[(r0  )*N + c0  ] - a00);
    Rp[(r0  )*N + c0+1] = (float)(Bp[(r0  )*N + c0+1] - a01);
    Rp[(r0+1)*N + c0  ] = (float)(Bp[(r0+1)*N + c0  ] - a10);
    Rp[(r0+1)*N + c0+1] = (float)(Bp[(r0+1)*N + c0+1] - a11);
}

// ---------------- X = X0 + G * R  (all f32, f64 accum) ----------------
__global__ void k_gemm_x(const float* __restrict__ Gden, const float* __restrict__ Rm,
                         const float* __restrict__ X0, float* __restrict__ Xm){
    int s = blockIdx.z;
    const float* Gp = Gden + s*N*N;
    const float* Rp = Rm + s*N*N;
    const float* X0p = X0 + s*N*N;
    float* Xp = Xm + s*N*N;
    __shared__ float Gs[32][33], Rs[32][33];
    int tx = threadIdx.x, ty = threadIdx.y;
    int tid = ty*16 + tx;
    int bj = blockIdx.y*32, bi = blockIdx.x*32;
    double a00=0, a01=0, a10=0, a11=0;
    for (int kc = 0; kc < N; kc += 32){
        __syncthreads();
        #pragma unroll
        for (int l = 0; l < 4; l++){
            int e = tid + l*256; int r = e >> 5, c = e & 31;
            Gs[r][c] = Gp[(bj+r)*N + kc + c];
            Rs[r][c] = Rp[(kc+r)*N + bi + c];
        }
        __syncthreads();
        #pragma unroll
        for (int k = 0; k < 32; k++){
            float x0 = Gs[2*ty][k], x1 = Gs[2*ty+1][k];
            float y0 = Rs[k][2*tx], y1 = Rs[k][2*tx+1];
            a00 += (double)x0*y0; a01 += (double)x0*y1;
            a10 += (double)x1*y0; a11 += (double)x1*y1;
        }
    }
    int r0 = bj+2*ty, c0 = bi+2*tx;
    Xp[(r0  )*N + c0  ] = (float)((double)X0p[(r0  )*N + c0  ] + a00);
    Xp[(r0  )*N + c0+1] = (float)((double)X0p[(r0  )*N + c0+1] + a01);
    Xp[(r0+1)*N + c0  ] = (float)((double)X0p[(r0+1)*N + c0  ] + a10);
    Xp[(r0+1)*N + c0+1] = (float)((double)X0p[(r0+1)*N + c0+1] + a11);
}

// ---------------- numerator solves: y = Gnum*b, + one IR step ----------------
__global__ void k_numsolve(const float* __restrict__ Gnum, const double* __restrict__ Anum,
                           const double* __restrict__ bnum, float* __restrict__ rnum){
    __shared__ double y0[256], rr[256], bsh[256];
    int s = blockIdx.x, j = threadIdx.x;
    const float* Gp = Gnum + s*N*N;
    const double* Ap = Anum + s*N*N;
    const double* bp = bnum + s*N;
    bsh[j] = bp[j];
    __syncthreads();
    double acc = 0;
    for (int k = 0; k < N; k++) acc += (double)Gp[j*N+k] * bsh[k];
    y0[j] = acc;
    __syncthreads();
    acc = 0;
    for (int k = 0; k < N; k++) acc += Ap[j*N+k] * y0[k];
    rr[j] = bsh[j] - acc;
    __syncthreads();
    acc = 0;
    for (int k = 0; k < N; k++) acc += (double)Gp[j*N+k] * rr[k];
    rnum[s*N+j] = (float)(y0[j] + acc);
}

// ---------------- final loss ----------------
__global__ void k_loss(const float* __restrict__ Xm, const float* __restrict__ rnum,
                       float* __restrict__ out){
    __shared__ double red[256];
    int i = threadIdx.x;
    double dsum = 0;
    for (int j = 0; j < N; j++){
        float sx = 0.25f*(Xm[0*N*N + j*N + i] + Xm[1*N*N + j*N + i] +
                          Xm[2*N*N + j*N + i] + Xm[3*N*N + j*N + i]);
        dsum += (double)fmaxf(sx, 0.f);
    }
    double denum = dsum + (double)N * 1.0e-3;
    float ravg = 0.25f*(rnum[0*N+i] + rnum[1*N+i] + rnum[2*N+i] + rnum[3*N+i]);
    double rn = (double)fmaxf(ravg, 0.f) + 1.0e-3;
    red[i] = log(rn) + log(denum);
    __syncthreads();
    for (int st = 128; st > 0; st >>= 1){
        if (i < st) red[i] += red[i + st];
        __syncthreads();
    }
    if (i == 0) out[0] = (float)red[0];
}

extern "C" void kernel_launch(void* const* d_in, const int* in_sizes, int n_in,
                              void* d_out, int out_size, void* d_ws, size_t ws_size,
                              hipStream_t stream) {
    (void)in_sizes; (void)n_in; (void)out_size; (void)ws_size;
    const float* z1 = (const float*)d_in[0];
    const float* z2 = (const float*)d_in[1];
    const int*   p1 = (const int*)d_in[2];
    const int*   p2 = (const int*)d_in[3];
    float* out = (float*)d_out;

    char* w = (char*)d_ws;
    size_t o = 0;
    auto carve = [&](size_t bytes) -> char* {
        char* p = w + o;
        o += (bytes + 255) & ~(size_t)255;
        return p;
    };
    float*  z1s  = (float*) carve(N*Dd*sizeof(float));
    float*  z2s  = (float*) carve(N*Dd*sizeof(float));
    float*  Dmat = (float*) carve((size_t)5*N*N*sizeof(float));
    double* Aden = (double*)carve((size_t)4*N*N*sizeof(double));
    double* Anum = (double*)carve((size_t)4*N*N*sizeof(double));
    float*  M4   = (float*) carve((size_t)4*N*N*sizeof(float));
    float*  U4   = (float*) carve((size_t)4*N*N*sizeof(float));
    double* Bmat = (double*)carve((size_t)4*N*N*sizeof(double));
    float*  Gden = (float*) carve((size_t)4*N*N*sizeof(float));
    float*  Gnum = (float*) carve((size_t)4*N*N*sizeof(float));
    float*  X0   = (float*) carve((size_t)4*N*N*sizeof(float));
    float*  Rm   = (float*) carve((size_t)4*N*N*sizeof(float));
    float*  Xm   = (float*) carve((size_t)4*N*N*sizeof(float));
    double* bnum = (double*)carve((size_t)4*N*sizeof(double));
    float*  rnum = (float*) carve((size_t)4*N*sizeof(float));
    double* Smat = (double*)carve((size_t)8*N*N*sizeof(double));
    double* Eg   = (double*)carve((size_t)8*224*32*sizeof(double));
    double* Pg   = (double*)carve((size_t)8*32*32*sizeof(double));

    k_gather<<<dim3((2*N*Dd)/256), dim3(256), 0, stream>>>(z1, z2, p1, p2, z1s, z2s);
    k_dist<<<dim3(16,16,5), dim3(16,16), 0, stream>>>(z1, z2, z1s, z2s, Dmat);
    k_kermat<<<dim3(N,16), dim3(256), 0, stream>>>(Dmat, Aden, Anum, M4, U4, Smat);
    k_bnum<<<dim3(N,4), dim3(256), 0, stream>>>(Dmat, bnum);

    for (int k = 0; k < 8; k++){
        k_pivot<<<dim3(8), dim3(1024), 0, stream>>>(Smat, Eg, Pg, k);
        k_step<<<dim3(56,8), dim3(256), 0, stream>>>(Smat, Eg, Pg, k);
    }
    k_gout<<<dim3(2048), dim3(256), 0, stream>>>(Smat, Gden, Gnum);

    k_gemm_nt<<<dim3(8,8,4), dim3(16,16), 0, stream>>>(M4, U4, Bmat);
    k_gemm_x0<<<dim3(8,8,4), dim3(16,16), 0, stream>>>(Gden, Bmat, X0);
    k_gemm_r<<<dim3(8,8,4), dim3(16,16), 0, stream>>>(Aden, X0, Bmat, Rm);
    k_gemm_x<<<dim3(8,8,4), dim3(16,16), 0, stream>>>(Gden, Rm, X0, Xm);
    k_numsolve<<<dim3(4), dim3(256), 0, stream>>>(Gnum, Anum, bnum, rnum);
    k_loss<<<dim3(1), dim3(256), 0, stream>>>(Xm, rnum, out);
}